// Round 1
// baseline (278.322 us; speedup 1.0000x reference)
//
#include <hip/hip_runtime.h>

#define HH 2160
#define WW 3840
#define NPATCH 256
#define PSZ 128
#define HW_ (HH*WW)
#define FMSZ (NPATCH*PSZ*PSZ)

#define TW 256
#define TH 32

// ---------------- zero accumulators ----------------
__global__ __launch_bounds__(64) void zero_acc_kernel(double* acc) {
    int t = threadIdx.x;
    if (t < 13) acc[t] = 0.0;
}

// ---------------- feather masks: separable 9-tap gaussian, zero-padded per patch ----------------
__global__ __launch_bounds__(256) void feather_kernel(
        const float* __restrict__ mask, const int* __restrict__ pos_y,
        const int* __restrict__ pos_x, float* __restrict__ fm) {
    __shared__ float sm[PSZ*PSZ];
    __shared__ float tp[PSZ*PSZ];
    const int n = blockIdx.x;
    const int y0 = pos_y[n], x0 = pos_x[n];
    float g[9]; float s = 0.f;
    #pragma unroll
    for (int k = 0; k < 9; ++k) { float xx = (k-4)*0.75f; g[k] = expf(-0.5f*xx*xx); s += g[k]; }
    const float inv = 1.f/s;
    #pragma unroll
    for (int k = 0; k < 9; ++k) g[k] *= inv;

    for (int idx = threadIdx.x; idx < PSZ*PSZ; idx += 256) {
        int i = idx >> 7, j = idx & 127;
        sm[idx] = mask[(y0+i)*WW + (x0+j)];
    }
    __syncthreads();
    for (int idx = threadIdx.x; idx < PSZ*PSZ; idx += 256) {
        int i = idx >> 7, j = idx & 127;
        float a = 0.f;
        #pragma unroll
        for (int d = -4; d <= 4; ++d) {
            int jj = j + d;
            if (jj >= 0 && jj < PSZ) a += sm[(i<<7)+jj]*g[d+4];
        }
        tp[idx] = a;
    }
    __syncthreads();
    float* o = fm + n*(PSZ*PSZ);
    for (int idx = threadIdx.x; idx < PSZ*PSZ; idx += 256) {
        int i = idx >> 7, j = idx & 127;
        float a = 0.f;
        #pragma unroll
        for (int d = -4; d <= 4; ++d) {
            int ii = i + d;
            if (ii >= 0 && ii < PSZ) a += tp[(ii<<7)+j]*g[d+4];
        }
        o[idx] = a;
    }
}

// ---------------- compose (per-pixel ordered fold) + masked stats ----------------
__global__ __launch_bounds__(256) void compose_kernel(
        const float* __restrict__ orig, const float* __restrict__ patches,
        const float* __restrict__ mask, const int* __restrict__ pos_y,
        const int* __restrict__ pos_x, const float* __restrict__ fm,
        float* __restrict__ out, double* __restrict__ acc) {
    __shared__ int ln[NPATCH];
    __shared__ int ly[NPATCH];
    __shared__ int lx[NPATCH];
    __shared__ unsigned long long wm[4];
    __shared__ float red[4][13];

    const int tid = threadIdx.x;
    const int tx0 = blockIdx.x * TW;
    const int ty0 = blockIdx.y * TH;

    // build ordered list of patches overlapping this tile (ascending n via prefix popcount)
    const int n = tid;                       // blockDim == NPATCH == 256
    const int yn = pos_y[n], xn = pos_x[n];
    const bool cov = (yn < ty0 + TH) && (yn + PSZ > ty0) &&
                     (xn < tx0 + TW) && (xn + PSZ > tx0);
    unsigned long long b = __ballot(cov);
    const int wid = tid >> 6;
    if ((tid & 63) == 0) wm[wid] = b;
    __syncthreads();
    const int cnt = __popcll(wm[0]) + __popcll(wm[1]) + __popcll(wm[2]) + __popcll(wm[3]);
    if (cov) {
        int pos = __popcll(b & ((1ull << (tid & 63)) - 1ull));
        for (int w = 0; w < wid; ++w) pos += __popcll(wm[w]);
        ln[pos] = n; ly[pos] = yn; lx[pos] = xn;
    }
    __syncthreads();

    const int x = tx0 + tid;
    float a_cnt = 0.f;
    float so1x=0,so1y=0,so1z=0, so2x=0,so2y=0,so2z=0;
    float sf1x=0,sf1y=0,sf1z=0, sf2x=0,sf2y=0,sf2z=0;

    for (int r = 0; r < TH; ++r) {
        const int y = ty0 + r;
        if (y >= HH) break;                  // uniform across block
        const int pix = y*WW + x;
        const float m = mask[pix];
        const float nh = 1.f - m;
        float v0 = orig[pix];
        float v1 = orig[HW_ + pix];
        float v2 = orig[2*HW_ + pix];
        a_cnt += nh;
        so1x += v0*nh; so2x += v0*v0*nh;
        so1y += v1*nh; so2y += v1*v1*nh;
        so1z += v2*nh; so2z += v2*v2*nh;
        for (int k = 0; k < cnt; ++k) {
            const int dy = y - ly[k];
            const int dx = x - lx[k];
            if (((unsigned)dy < (unsigned)PSZ) && ((unsigned)dx < (unsigned)PSZ)) {
                const int nn = ln[k];
                const int po = (dy << 7) + dx;
                const float f = fm[nn*(PSZ*PSZ) + po];
                const float of = 1.f - f;
                const int pb = nn*(3*PSZ*PSZ) + po;
                v0 = v0*of + patches[pb]*f;
                v1 = v1*of + patches[pb + PSZ*PSZ]*f;
                v2 = v2*of + patches[pb + 2*PSZ*PSZ]*f;
            }
        }
        out[pix] = v0; out[HW_+pix] = v1; out[2*HW_+pix] = v2;
        sf1x += v0*nh; sf2x += v0*v0*nh;
        sf1y += v1*nh; sf2y += v1*v1*nh;
        sf1z += v2*nh; sf2z += v2*v2*nh;
    }

    float vals[13] = {a_cnt, so1x,so1y,so1z, so2x,so2y,so2z,
                      sf1x,sf1y,sf1z, sf2x,sf2y,sf2z};
    #pragma unroll
    for (int v = 0; v < 13; ++v) {
        float t = vals[v];
        t += __shfl_down(t, 32); t += __shfl_down(t, 16);
        t += __shfl_down(t, 8);  t += __shfl_down(t, 4);
        t += __shfl_down(t, 2);  t += __shfl_down(t, 1);
        if ((tid & 63) == 0) red[wid][v] = t;
    }
    __syncthreads();
    if (tid < 13) {
        float sgl = red[0][tid] + red[1][tid] + red[2][tid] + red[3][tid];
        atomicAdd(&acc[tid], (double)sgl);
    }
}

// ---------------- finalize per-channel coefficients ----------------
__global__ void finalize_kernel(const double* __restrict__ acc, float* __restrict__ coef) {
    if (threadIdx.x == 0 && blockIdx.x == 0) {
        const double cnt = acc[0];
        for (int c = 0; c < 3; ++c) {
            double om = acc[1+c]/cnt;
            double ov = acc[4+c]/cnt - om*om;
            double os = sqrt(ov > 0.0 ? ov : 0.0);
            double fmn = acc[7+c]/cnt;
            double fv = acc[10+c]/cnt - fmn*fmn;
            double fs = sqrt(fv > 0.0 ? fv : 0.0);
            double ratio = os/(fs + 1e-8);
            coef[c]   = (float)ratio;
            coef[3+c] = (float)fmn;
            coef[6+c] = (float)om;
        }
    }
}

// ---------------- color correction, float4 ----------------
__global__ __launch_bounds__(256) void correct_kernel(
        float* __restrict__ out, const float* __restrict__ mask,
        const float* __restrict__ coef) {
    const int e4 = blockIdx.x * 256 + threadIdx.x;
    const int n4 = (3*HW_)/4;
    if (e4 >= n4) return;
    const int e = e4 * 4;
    const int plane = e / HW_;          // 4 elems never straddle planes (HW_ % 4 == 0)
    const int pix = e - plane*HW_;
    const float ratio = coef[plane], fmn = coef[3+plane], om = coef[6+plane];
    float4 v = reinterpret_cast<float4*>(out)[e4];
    const float4 m = reinterpret_cast<const float4*>(mask)[pix >> 2];
    v.x = v.x*(1.f-m.x) + ((v.x*m.x - fmn)*ratio + om)*m.x;
    v.y = v.y*(1.f-m.y) + ((v.y*m.y - fmn)*ratio + om)*m.y;
    v.z = v.z*(1.f-m.z) + ((v.z*m.z - fmn)*ratio + om)*m.z;
    v.w = v.w*(1.f-m.w) + ((v.w*m.w - fmn)*ratio + om)*m.w;
    reinterpret_cast<float4*>(out)[e4] = v;
}

extern "C" void kernel_launch(void* const* d_in, const int* in_sizes, int n_in,
                              void* d_out, int out_size, void* d_ws, size_t ws_size,
                              hipStream_t stream) {
    const float* orig    = (const float*)d_in[0];
    const float* patches = (const float*)d_in[1];
    const float* mask    = (const float*)d_in[2];
    const int*   pos_y   = (const int*)d_in[3];
    const int*   pos_x   = (const int*)d_in[4];
    float* out = (float*)d_out;

    float*  fm   = (float*)d_ws;
    double* acc  = (double*)((char*)d_ws + (size_t)FMSZ*4);
    float*  coef = (float*)((char*)d_ws + (size_t)FMSZ*4 + 16*8);

    zero_acc_kernel<<<1, 64, 0, stream>>>(acc);
    feather_kernel<<<NPATCH, 256, 0, stream>>>(mask, pos_y, pos_x, fm);
    dim3 g(WW/TW, (HH + TH - 1)/TH);
    compose_kernel<<<g, 256, 0, stream>>>(orig, patches, mask, pos_y, pos_x, fm, out, acc);
    finalize_kernel<<<1, 64, 0, stream>>>(acc, coef);
    const int n4 = (3*HW_)/4;
    correct_kernel<<<(n4 + 255)/256, 256, 0, stream>>>(out, mask, coef);
}

// Round 2
// 241.182 us; speedup vs baseline: 1.1540x; 1.1540x over previous
//
#include <hip/hip_runtime.h>

#define HH 2160
#define WW 3840
#define NPATCH 256
#define PSZ 128
#define HW_ (HH*WW)
#define FMSZ (NPATCH*PSZ*PSZ)

#define TW 256
#define TH 8
#define NBX (WW/TW)     // 15
#define NBY (HH/TH)     // 270
#define NB  (NBX*NBY)   // 4050

// ---------------- feather masks: separable 9-tap gaussian, zero-padded per patch ----------------
__global__ __launch_bounds__(256) void feather_kernel(
        const float* __restrict__ mask, const int* __restrict__ pos_y,
        const int* __restrict__ pos_x, float* __restrict__ fm) {
    __shared__ float sm[PSZ*PSZ];
    __shared__ float tp[PSZ*PSZ];
    const int n = blockIdx.x;
    const int y0 = pos_y[n], x0 = pos_x[n];
    float g[9]; float s = 0.f;
    #pragma unroll
    for (int k = 0; k < 9; ++k) { float xx = (k-4)*0.75f; g[k] = expf(-0.5f*xx*xx); s += g[k]; }
    const float inv = 1.f/s;
    #pragma unroll
    for (int k = 0; k < 9; ++k) g[k] *= inv;

    for (int idx = threadIdx.x; idx < PSZ*PSZ; idx += 256) {
        int i = idx >> 7, j = idx & 127;
        sm[idx] = mask[(y0+i)*WW + (x0+j)];
    }
    __syncthreads();
    for (int idx = threadIdx.x; idx < PSZ*PSZ; idx += 256) {
        int i = idx >> 7, j = idx & 127;
        float a = 0.f;
        #pragma unroll
        for (int d = -4; d <= 4; ++d) {
            int jj = j + d;
            if (jj >= 0 && jj < PSZ) a += sm[(i<<7)+jj]*g[d+4];
        }
        tp[idx] = a;
    }
    __syncthreads();
    float* o = fm + n*(PSZ*PSZ);
    for (int idx = threadIdx.x; idx < PSZ*PSZ; idx += 256) {
        int i = idx >> 7, j = idx & 127;
        float a = 0.f;
        #pragma unroll
        for (int d = -4; d <= 4; ++d) {
            int ii = i + d;
            if (ii >= 0 && ii < PSZ) a += tp[(ii<<7)+j]*g[d+4];
        }
        o[idx] = a;
    }
}

// ---------------- compose (per-pixel ordered fold, float4) + per-block stat partials ----------------
__global__ __launch_bounds__(256) void compose_kernel(
        const float* __restrict__ orig, const float* __restrict__ patches,
        const float* __restrict__ mask, const int* __restrict__ pos_y,
        const int* __restrict__ pos_x, const float* __restrict__ fm,
        float* __restrict__ out, float* __restrict__ partial) {
    __shared__ int ln[NPATCH];
    __shared__ int ly[NPATCH];
    __shared__ int lx[NPATCH];
    __shared__ unsigned long long wm[4];
    __shared__ float red[4][13];

    const int tid = threadIdx.x;
    const int tx0 = blockIdx.x * TW;
    const int ty0 = blockIdx.y * TH;

    // ordered list (ascending n) of patches overlapping this 256x8 tile
    {
        const int yn = pos_y[tid], xn = pos_x[tid];
        const bool cov = (yn < ty0 + TH) && (yn + PSZ > ty0) &&
                         (xn < tx0 + TW) && (xn + PSZ > tx0);
        unsigned long long b = __ballot(cov);
        const int wid = tid >> 6;
        if ((tid & 63) == 0) wm[wid] = b;
        __syncthreads();
        if (cov) {
            int pos = __popcll(b & ((1ull << (tid & 63)) - 1ull));
            for (int w = 0; w < wid; ++w) pos += __popcll(wm[w]);
            ln[pos] = tid; ly[pos] = yn; lx[pos] = xn;
        }
        __syncthreads();
    }
    const int cnt = __popcll(wm[0]) + __popcll(wm[1]) + __popcll(wm[2]) + __popcll(wm[3]);

    const int lane = tid & 63;
    const int wid  = tid >> 6;
    const int x0 = tx0 + lane * 4;          // each thread owns a pixel quad

    float a_cnt = 0.f;
    float so1x=0,so1y=0,so1z=0, so2x=0,so2y=0,so2z=0;
    float sf1x=0,sf1y=0,sf1z=0, sf2x=0,sf2y=0,sf2z=0;

    const float4* __restrict__ mask4 = (const float4*)mask;
    const float4* __restrict__ orig4 = (const float4*)orig;
    float4* __restrict__ out4 = (float4*)out;

    #pragma unroll
    for (int rr = 0; rr < 2; ++rr) {
        const int y = ty0 + wid * 2 + rr;   // wave covers a full 256-px row
        const int pix = y*WW + x0;
        const int q = pix >> 2;
        const float4 m = mask4[q];
        float4 v0 = orig4[q];
        float4 v1 = orig4[(HW_ >> 2) + q];
        float4 v2 = orig4[((2*HW_) >> 2) + q];

        const float nhx = 1.f-m.x, nhy = 1.f-m.y, nhz = 1.f-m.z, nhw = 1.f-m.w;
        a_cnt += nhx+nhy+nhz+nhw;
        so1x += v0.x*nhx+v0.y*nhy+v0.z*nhz+v0.w*nhw;
        so2x += v0.x*v0.x*nhx+v0.y*v0.y*nhy+v0.z*v0.z*nhz+v0.w*v0.w*nhw;
        so1y += v1.x*nhx+v1.y*nhy+v1.z*nhz+v1.w*nhw;
        so2y += v1.x*v1.x*nhx+v1.y*v1.y*nhy+v1.z*v1.z*nhz+v1.w*v1.w*nhw;
        so1z += v2.x*nhx+v2.y*nhy+v2.z*nhz+v2.w*nhw;
        so2z += v2.x*v2.x*nhx+v2.y*v2.y*nhy+v2.z*v2.z*nhz+v2.w*v2.w*nhw;

        for (int k = 0; k < cnt; ++k) {
            const int dy = y - ly[k];
            if ((unsigned)dy >= (unsigned)PSZ) continue;
            const int dx0 = x0 - lx[k];
            if (dx0 <= -4 || dx0 >= PSZ) continue;
            const int nn = ln[k];
            const int rowb = dy << 7;
            const float* __restrict__ fmp = fm + nn*(PSZ*PSZ) + rowb;
            const float* __restrict__ pp  = patches + nn*(3*PSZ*PSZ) + rowb;
            #define BLEND(J, MX) { \
                const int dx = dx0 + J; \
                if ((unsigned)dx < (unsigned)PSZ) { \
                    const float f = fmp[dx]; const float of = 1.f - f; \
                    v0.MX = v0.MX*of + pp[dx]*f; \
                    v1.MX = v1.MX*of + pp[dx + PSZ*PSZ]*f; \
                    v2.MX = v2.MX*of + pp[dx + 2*PSZ*PSZ]*f; \
                } }
            BLEND(0, x) BLEND(1, y) BLEND(2, z) BLEND(3, w)
            #undef BLEND
        }

        out4[q] = v0;
        out4[(HW_ >> 2) + q] = v1;
        out4[((2*HW_) >> 2) + q] = v2;

        sf1x += v0.x*nhx+v0.y*nhy+v0.z*nhz+v0.w*nhw;
        sf2x += v0.x*v0.x*nhx+v0.y*v0.y*nhy+v0.z*v0.z*nhz+v0.w*v0.w*nhw;
        sf1y += v1.x*nhx+v1.y*nhy+v1.z*nhz+v1.w*nhw;
        sf2y += v1.x*v1.x*nhx+v1.y*v1.y*nhy+v1.z*v1.z*nhz+v1.w*v1.w*nhw;
        sf1z += v2.x*nhx+v2.y*nhy+v2.z*nhz+v2.w*nhw;
        sf2z += v2.x*v2.x*nhx+v2.y*v2.y*nhy+v2.z*v2.z*nhz+v2.w*v2.w*nhw;
    }

    float vals[13] = {a_cnt, so1x,so1y,so1z, so2x,so2y,so2z,
                      sf1x,sf1y,sf1z, sf2x,sf2y,sf2z};
    #pragma unroll
    for (int v = 0; v < 13; ++v) {
        float t = vals[v];
        t += __shfl_down(t, 32); t += __shfl_down(t, 16);
        t += __shfl_down(t, 8);  t += __shfl_down(t, 4);
        t += __shfl_down(t, 2);  t += __shfl_down(t, 1);
        if (lane == 0) red[wid][v] = t;
    }
    __syncthreads();
    if (tid < 13) {
        const int bid = blockIdx.y * NBX + blockIdx.x;
        partial[bid*13 + tid] = red[0][tid] + red[1][tid] + red[2][tid] + red[3][tid];
    }
}

// ---------------- reduce partials, emit per-channel coefficients ----------------
__global__ __launch_bounds__(256) void finalize_kernel(
        const float* __restrict__ partial, float* __restrict__ coef) {
    __shared__ double red[13][16];
    __shared__ double tot[13];
    const int t = threadIdx.x;
    if (t < 208) {
        const int v = t >> 4, sub = t & 15;
        double s = 0.0;
        for (int b = sub; b < NB; b += 16) s += (double)partial[b*13 + v];
        red[v][sub] = s;
    }
    __syncthreads();
    if (t < 13) {
        double s = 0.0;
        #pragma unroll
        for (int i = 0; i < 16; ++i) s += red[t][i];
        tot[t] = s;
    }
    __syncthreads();
    if (t < 3) {
        const double cnt = tot[0];
        double om = tot[1+t]/cnt;
        double ov = tot[4+t]/cnt - om*om;
        double os = sqrt(ov > 0.0 ? ov : 0.0);
        double fmn = tot[7+t]/cnt;
        double fv = tot[10+t]/cnt - fmn*fmn;
        double fs = sqrt(fv > 0.0 ? fv : 0.0);
        coef[t]   = (float)(os/(fs + 1e-8));
        coef[3+t] = (float)fmn;
        coef[6+t] = (float)om;
    }
}

// ---------------- color correction: binary mask -> touch only hole quads ----------------
__global__ __launch_bounds__(256) void correct_kernel(
        float* __restrict__ out, const float* __restrict__ mask,
        const float* __restrict__ coef) {
    const int q = blockIdx.x * 256 + threadIdx.x;   // pixel quad within a plane
    if (q >= (HW_ >> 2)) return;
    const float4 m = ((const float4*)mask)[q];
    if (m.x == 0.f && m.y == 0.f && m.z == 0.f && m.w == 0.f) return;
    float4* __restrict__ out4 = (float4*)out;
    #pragma unroll
    for (int c = 0; c < 3; ++c) {
        const float ratio = coef[c], fmn = coef[3+c], om = coef[6+c];
        float4 v = out4[c*(HW_ >> 2) + q];
        if (m.x != 0.f) v.x = (v.x - fmn)*ratio + om;
        if (m.y != 0.f) v.y = (v.y - fmn)*ratio + om;
        if (m.z != 0.f) v.z = (v.z - fmn)*ratio + om;
        if (m.w != 0.f) v.w = (v.w - fmn)*ratio + om;
        out4[c*(HW_ >> 2) + q] = v;
    }
}

extern "C" void kernel_launch(void* const* d_in, const int* in_sizes, int n_in,
                              void* d_out, int out_size, void* d_ws, size_t ws_size,
                              hipStream_t stream) {
    const float* orig    = (const float*)d_in[0];
    const float* patches = (const float*)d_in[1];
    const float* mask    = (const float*)d_in[2];
    const int*   pos_y   = (const int*)d_in[3];
    const int*   pos_x   = (const int*)d_in[4];
    float* out = (float*)d_out;

    float* fm      = (float*)d_ws;
    float* partial = (float*)((char*)d_ws + (size_t)FMSZ*4);
    float* coef    = (float*)((char*)d_ws + (size_t)FMSZ*4 + (size_t)NB*13*4);

    feather_kernel<<<NPATCH, 256, 0, stream>>>(mask, pos_y, pos_x, fm);
    dim3 g(NBX, NBY);
    compose_kernel<<<g, 256, 0, stream>>>(orig, patches, mask, pos_y, pos_x, fm, out, partial);
    finalize_kernel<<<1, 256, 0, stream>>>(partial, coef);
    correct_kernel<<<((HW_ >> 2) + 255)/256, 256, 0, stream>>>(out, mask, coef);
}

// Round 3
// 176.598 us; speedup vs baseline: 1.5760x; 1.3657x over previous
//
#include <hip/hip_runtime.h>

#define HH 2160
#define WW 3840
#define NPATCH 256
#define PSZ 128
#define HW_ (HH*WW)
#define FMSZ (NPATCH*PSZ*PSZ)

#define TW 256
#define TH 8
#define NBX (WW/TW)     // 15
#define NBY (HH/TH)     // 270
#define NB  (NBX*NBY)   // 4050

// ws layout: fm | acc(13 dbl) | counter(u32) | coef(9 f32) | hole list
#define ACC_OFF   ((size_t)FMSZ*4)
#define CNT_OFF   (ACC_OFF + 104)
#define COEF_OFF  (ACC_OFF + 112)
#define LIST_OFF  (ACC_OFF + 160)

// ---------------- zero accumulators + counter ----------------
__global__ __launch_bounds__(64) void zero_acc_kernel(double* acc, unsigned int* counter) {
    int t = threadIdx.x;
    if (t < 13) acc[t] = 0.0;
    if (t == 13) *counter = 0u;
}

// ---------------- feather: separable 9-tap gaussian, zero-padded per patch ----------------
// grid (NPATCH, 4): each block computes 32 output rows with +-4 halo in LDS
__global__ __launch_bounds__(256) void feather_kernel(
        const float* __restrict__ mask, const int* __restrict__ pos_y,
        const int* __restrict__ pos_x, float* __restrict__ fm) {
    __shared__ float sm[40*PSZ];
    __shared__ float tp[40*PSZ];
    const int n = blockIdx.x;
    const int r0 = blockIdx.y * 32;
    const int y0 = pos_y[n], x0 = pos_x[n];
    float g[9]; float s = 0.f;
    #pragma unroll
    for (int k = 0; k < 9; ++k) { float xx = (k-4)*0.75f; g[k] = expf(-0.5f*xx*xx); s += g[k]; }
    const float inv = 1.f/s;
    #pragma unroll
    for (int k = 0; k < 9; ++k) g[k] *= inv;

    for (int idx = threadIdx.x; idx < 40*PSZ; idx += 256) {
        int l = idx >> 7, j = idx & 127;
        int r = r0 + l - 4;
        sm[idx] = ((unsigned)r < (unsigned)PSZ) ? mask[(y0+r)*WW + (x0+j)] : 0.f;
    }
    __syncthreads();
    for (int idx = threadIdx.x; idx < 40*PSZ; idx += 256) {
        int l = idx >> 7, j = idx & 127;
        float a = 0.f;
        #pragma unroll
        for (int d = -4; d <= 4; ++d) {
            int jj = j + d;
            if (jj >= 0 && jj < PSZ) a += sm[(l<<7)+jj]*g[d+4];
        }
        tp[idx] = a;
    }
    __syncthreads();
    float* o = fm + n*(PSZ*PSZ) + r0*PSZ;
    for (int idx = threadIdx.x; idx < 32*PSZ; idx += 256) {
        int i = idx >> 7, j = idx & 127;
        float a = 0.f;
        #pragma unroll
        for (int d = 0; d < 9; ++d) a += tp[((i+d)<<7)+j]*g[d];
        o[idx] = a;
    }
}

// ---------------- compose: ordered per-pixel fold (2 rows/thread merged), stats atomics, hole list ----------------
__global__ __launch_bounds__(256) void compose_kernel(
        const float* __restrict__ orig, const float* __restrict__ patches,
        const float* __restrict__ mask, const int* __restrict__ pos_y,
        const int* __restrict__ pos_x, const float* __restrict__ fm,
        float* __restrict__ out, double* __restrict__ acc,
        unsigned int* __restrict__ counter, unsigned int* __restrict__ list,
        unsigned int cap) {
    __shared__ int ln[NPATCH];
    __shared__ int ly[NPATCH];
    __shared__ int lx[NPATCH];
    __shared__ unsigned long long wm[4];
    __shared__ float red[4][13];
    __shared__ unsigned int hcnt[9];

    const int tid = threadIdx.x;
    const int lane = tid & 63;
    const int wid  = tid >> 6;
    const int tx0 = blockIdx.x * TW;
    const int ty0 = blockIdx.y * TH;

    // ordered (ascending n) list of patches overlapping this 256x8 tile
    {
        const int yn = pos_y[tid], xn = pos_x[tid];
        const bool cov = (yn < ty0 + TH) && (yn + PSZ > ty0) &&
                         (xn < tx0 + TW) && (xn + PSZ > tx0);
        unsigned long long b = __ballot(cov);
        if (lane == 0) wm[wid] = b;
        __syncthreads();
        if (cov) {
            int pos = __popcll(b & ((1ull << lane) - 1ull));
            for (int w = 0; w < wid; ++w) pos += __popcll(wm[w]);
            ln[pos] = tid; ly[pos] = yn; lx[pos] = xn;
        }
        __syncthreads();
    }
    const int cnt = __popcll(wm[0]) + __popcll(wm[1]) + __popcll(wm[2]) + __popcll(wm[3]);

    const int x0 = tx0 + lane * 4;           // this thread's pixel quad column
    const int y  = ty0 + wid * 2;            // rows y and y+1

    const float4* __restrict__ mask4 = (const float4*)mask;
    const float4* __restrict__ orig4 = (const float4*)orig;
    float4* __restrict__ out4 = (float4*)out;

    const int q0 = (y*WW + x0) >> 2;
    const int q1 = q0 + (WW >> 2);
    const float4 mA = mask4[q0];
    const float4 mB = mask4[q1];
    float4 a0 = orig4[q0],              b0 = orig4[q1];
    float4 a1 = orig4[(HW_>>2)+q0],     b1 = orig4[(HW_>>2)+q1];
    float4 a2 = orig4[((2*HW_)>>2)+q0], b2 = orig4[((2*HW_)>>2)+q1];

    const float nAx=1.f-mA.x, nAy=1.f-mA.y, nAz=1.f-mA.z, nAw=1.f-mA.w;
    const float nBx=1.f-mB.x, nBy=1.f-mB.y, nBz=1.f-mB.z, nBw=1.f-mB.w;

    float a_cnt = nAx+nAy+nAz+nAw + nBx+nBy+nBz+nBw;
    float so1x = a0.x*nAx+a0.y*nAy+a0.z*nAz+a0.w*nAw + b0.x*nBx+b0.y*nBy+b0.z*nBz+b0.w*nBw;
    float so2x = a0.x*a0.x*nAx+a0.y*a0.y*nAy+a0.z*a0.z*nAz+a0.w*a0.w*nAw
               + b0.x*b0.x*nBx+b0.y*b0.y*nBy+b0.z*b0.z*nBz+b0.w*b0.w*nBw;
    float so1y = a1.x*nAx+a1.y*nAy+a1.z*nAz+a1.w*nAw + b1.x*nBx+b1.y*nBy+b1.z*nBz+b1.w*nBw;
    float so2y = a1.x*a1.x*nAx+a1.y*a1.y*nAy+a1.z*a1.z*nAz+a1.w*a1.w*nAw
               + b1.x*b1.x*nBx+b1.y*b1.y*nBy+b1.z*b1.z*nBz+b1.w*b1.w*nBw;
    float so1z = a2.x*nAx+a2.y*nAy+a2.z*nAz+a2.w*nAw + b2.x*nBx+b2.y*nBy+b2.z*nBz+b2.w*nBw;
    float so2z = a2.x*a2.x*nAx+a2.y*a2.y*nAy+a2.z*a2.z*nAz+a2.w*a2.w*nAw
               + b2.x*b2.x*nBx+b2.y*b2.y*nBy+b2.z*b2.z*nBz+b2.w*b2.w*nBw;

    for (int k = 0; k < cnt; ++k) {
        const int dy0 = y - ly[k];
        if ((unsigned)(dy0+1) >= (unsigned)(PSZ+1)) continue;   // neither row in patch
        const int dx0 = x0 - lx[k];
        if (dx0 <= -4 || dx0 >= PSZ) continue;
        const int nn = ln[k];
        const float* __restrict__ fmb = fm + nn*(PSZ*PSZ);
        const float* __restrict__ ppb = patches + nn*(3*PSZ*PSZ);
        const bool r0v = (unsigned)dy0 < (unsigned)PSZ;
        const bool r1v = (unsigned)(dy0+1) < (unsigned)PSZ;
        const int ro0 = dy0 << 7, ro1 = (dy0+1) << 7;
        #define BLEND(J, MX) { \
            const int dx = dx0 + J; \
            if ((unsigned)dx < (unsigned)PSZ) { \
                if (r0v) { \
                    const float f = fmb[ro0+dx]; const float of = 1.f - f; \
                    a0.MX = a0.MX*of + ppb[ro0+dx]*f; \
                    a1.MX = a1.MX*of + ppb[ro0+dx + PSZ*PSZ]*f; \
                    a2.MX = a2.MX*of + ppb[ro0+dx + 2*PSZ*PSZ]*f; \
                } \
                if (r1v) { \
                    const float f = fmb[ro1+dx]; const float of = 1.f - f; \
                    b0.MX = b0.MX*of + ppb[ro1+dx]*f; \
                    b1.MX = b1.MX*of + ppb[ro1+dx + PSZ*PSZ]*f; \
                    b2.MX = b2.MX*of + ppb[ro1+dx + 2*PSZ*PSZ]*f; \
                } \
            } }
        BLEND(0, x) BLEND(1, y) BLEND(2, z) BLEND(3, w)
        #undef BLEND
    }

    out4[q0] = a0; out4[(HW_>>2)+q0] = a1; out4[((2*HW_)>>2)+q0] = a2;
    out4[q1] = b0; out4[(HW_>>2)+q1] = b1; out4[((2*HW_)>>2)+q1] = b2;

    float sf1x = a0.x*nAx+a0.y*nAy+a0.z*nAz+a0.w*nAw + b0.x*nBx+b0.y*nBy+b0.z*nBz+b0.w*nBw;
    float sf2x = a0.x*a0.x*nAx+a0.y*a0.y*nAy+a0.z*a0.z*nAz+a0.w*a0.w*nAw
               + b0.x*b0.x*nBx+b0.y*b0.y*nBy+b0.z*b0.z*nBz+b0.w*b0.w*nBw;
    float sf1y = a1.x*nAx+a1.y*nAy+a1.z*nAz+a1.w*nAw + b1.x*nBx+b1.y*nBy+b1.z*nBz+b1.w*nBw;
    float sf2y = a1.x*a1.x*nAx+a1.y*a1.y*nAy+a1.z*a1.z*nAz+a1.w*a1.w*nAw
               + b1.x*b1.x*nBx+b1.y*b1.y*nBy+b1.z*b1.z*nBz+b1.w*b1.w*nBw;
    float sf1z = a2.x*nAx+a2.y*nAy+a2.z*nAz+a2.w*nAw + b2.x*nBx+b2.y*nBy+b2.z*nBz+b2.w*nBw;
    float sf2z = a2.x*a2.x*nAx+a2.y*a2.y*nAy+a2.z*a2.z*nAz+a2.w*a2.w*nAw
               + b2.x*b2.x*nBx+b2.y*b2.y*nBy+b2.z*b2.z*nBz+b2.w*b2.w*nBw;

    // --- hole-quad list (block compaction, 1 atomic per block) ---
    const unsigned int hb0 = (mA.x!=0.f) | ((mA.y!=0.f)<<1) | ((mA.z!=0.f)<<2) | ((mA.w!=0.f)<<3);
    const unsigned int hb1 = (mB.x!=0.f) | ((mB.y!=0.f)<<1) | ((mB.z!=0.f)<<2) | ((mB.w!=0.f)<<3);
    const unsigned long long bal0 = __ballot(hb0 != 0u);
    const unsigned long long bal1 = __ballot(hb1 != 0u);
    if (lane == 0) { hcnt[wid*2] = (unsigned)__popcll(bal0); hcnt[wid*2+1] = (unsigned)__popcll(bal1); }
    __syncthreads();
    if (tid == 0) {
        unsigned s = 0;
        #pragma unroll
        for (int i = 0; i < 8; ++i) { unsigned c = hcnt[i]; hcnt[i] = s; s += c; }
        hcnt[8] = atomicAdd(counter, s);
    }
    __syncthreads();
    {
        const unsigned base = hcnt[8];
        const unsigned long long lmask = (1ull << lane) - 1ull;
        if (hb0) {
            unsigned p = base + hcnt[wid*2] + (unsigned)__popcll(bal0 & lmask);
            if (p < cap) list[p] = ((unsigned)q0 << 4) | hb0;
        }
        if (hb1) {
            unsigned p = base + hcnt[wid*2+1] + (unsigned)__popcll(bal1 & lmask);
            if (p < cap) list[p] = ((unsigned)q1 << 4) | hb1;
        }
    }

    // --- stat partials: wave shuffle + cross-wave + 13 double atomics ---
    float vals[13] = {a_cnt, so1x,so1y,so1z, so2x,so2y,so2z,
                      sf1x,sf1y,sf1z, sf2x,sf2y,sf2z};
    #pragma unroll
    for (int v = 0; v < 13; ++v) {
        float t = vals[v];
        t += __shfl_down(t, 32); t += __shfl_down(t, 16);
        t += __shfl_down(t, 8);  t += __shfl_down(t, 4);
        t += __shfl_down(t, 2);  t += __shfl_down(t, 1);
        if (lane == 0) red[wid][v] = t;
    }
    __syncthreads();
    if (tid < 13) {
        float sgl = red[0][tid] + red[1][tid] + red[2][tid] + red[3][tid];
        atomicAdd(&acc[tid], (double)sgl);
    }
}

// ---------------- finalize: 13 doubles -> 9 coefficients ----------------
__global__ __launch_bounds__(64) void finalize_kernel(
        const double* __restrict__ acc, float* __restrict__ coef) {
    if (threadIdx.x == 0) {
        const double cnt = acc[0];
        for (int c = 0; c < 3; ++c) {
            double om = acc[1+c]/cnt;
            double ov = acc[4+c]/cnt - om*om;
            double os = sqrt(ov > 0.0 ? ov : 0.0);
            double fmn = acc[7+c]/cnt;
            double fv = acc[10+c]/cnt - fmn*fmn;
            double fs = sqrt(fv > 0.0 ? fv : 0.0);
            coef[c]   = (float)(os/(fs + 1e-8));
            coef[3+c] = (float)fmn;
            coef[6+c] = (float)om;
        }
    }
}

// ---------------- correct: only listed hole quads, no mask read ----------------
__global__ __launch_bounds__(256) void correct_kernel(
        float* __restrict__ out, const unsigned int* __restrict__ list,
        const unsigned int* __restrict__ counter, const float* __restrict__ coef,
        unsigned int cap) {
    unsigned n = *counter; if (n > cap) n = cap;
    const float r0 = coef[0], r1 = coef[1], r2 = coef[2];
    const float f0 = coef[3], f1 = coef[4], f2 = coef[5];
    const float o0 = coef[6], o1 = coef[7], o2 = coef[8];
    float4* __restrict__ out4 = (float4*)out;
    for (unsigned i = blockIdx.x*256u + threadIdx.x; i < n; i += gridDim.x*256u) {
        const unsigned e = list[i];
        const unsigned q = e >> 4, bits = e & 15u;
        float4 v0 = out4[q];
        float4 v1 = out4[(HW_>>2)+q];
        float4 v2 = out4[((2*HW_)>>2)+q];
        if (bits & 1u) { v0.x=(v0.x-f0)*r0+o0; v1.x=(v1.x-f1)*r1+o1; v2.x=(v2.x-f2)*r2+o2; }
        if (bits & 2u) { v0.y=(v0.y-f0)*r0+o0; v1.y=(v1.y-f1)*r1+o1; v2.y=(v2.y-f2)*r2+o2; }
        if (bits & 4u) { v0.z=(v0.z-f0)*r0+o0; v1.z=(v1.z-f1)*r1+o1; v2.z=(v2.z-f2)*r2+o2; }
        if (bits & 8u) { v0.w=(v0.w-f0)*r0+o0; v1.w=(v1.w-f1)*r1+o1; v2.w=(v2.w-f2)*r2+o2; }
        out4[q] = v0;
        out4[(HW_>>2)+q] = v1;
        out4[((2*HW_)>>2)+q] = v2;
    }
}

// ---------------- fallback correct (mask-based) if ws too small for list ----------------
__global__ __launch_bounds__(256) void correct_full_kernel(
        float* __restrict__ out, const float* __restrict__ mask,
        const float* __restrict__ coef) {
    const int q = blockIdx.x * 256 + threadIdx.x;
    if (q >= (HW_ >> 2)) return;
    const float4 m = ((const float4*)mask)[q];
    if (m.x == 0.f && m.y == 0.f && m.z == 0.f && m.w == 0.f) return;
    float4* __restrict__ out4 = (float4*)out;
    #pragma unroll
    for (int c = 0; c < 3; ++c) {
        const float ratio = coef[c], fmn = coef[3+c], om = coef[6+c];
        float4 v = out4[c*(HW_ >> 2) + q];
        if (m.x != 0.f) v.x = (v.x - fmn)*ratio + om;
        if (m.y != 0.f) v.y = (v.y - fmn)*ratio + om;
        if (m.z != 0.f) v.z = (v.z - fmn)*ratio + om;
        if (m.w != 0.f) v.w = (v.w - fmn)*ratio + om;
        out4[c*(HW_ >> 2) + q] = v;
    }
}

extern "C" void kernel_launch(void* const* d_in, const int* in_sizes, int n_in,
                              void* d_out, int out_size, void* d_ws, size_t ws_size,
                              hipStream_t stream) {
    const float* orig    = (const float*)d_in[0];
    const float* patches = (const float*)d_in[1];
    const float* mask    = (const float*)d_in[2];
    const int*   pos_y   = (const int*)d_in[3];
    const int*   pos_x   = (const int*)d_in[4];
    float* out = (float*)d_out;

    float*        fm      = (float*)d_ws;
    double*       acc     = (double*)((char*)d_ws + ACC_OFF);
    unsigned int* counter = (unsigned int*)((char*)d_ws + CNT_OFF);
    float*        coef    = (float*)((char*)d_ws + COEF_OFF);
    unsigned int* list    = (unsigned int*)((char*)d_ws + LIST_OFF);

    unsigned int cap = 0;
    if (ws_size > LIST_OFF) {
        size_t avail = (ws_size - LIST_OFF) / 4;
        cap = (avail > 2097152u) ? 2097152u : (unsigned int)avail;
    }
    const bool use_list = (cap >= 600000u);   // ~383K expected hole quads
    if (!use_list) cap = 0;

    zero_acc_kernel<<<1, 64, 0, stream>>>(acc, counter);
    dim3 fg(NPATCH, 4);
    feather_kernel<<<fg, 256, 0, stream>>>(mask, pos_y, pos_x, fm);
    dim3 g(NBX, NBY);
    compose_kernel<<<g, 256, 0, stream>>>(orig, patches, mask, pos_y, pos_x, fm,
                                          out, acc, counter, list, cap);
    finalize_kernel<<<1, 64, 0, stream>>>(acc, coef);
    if (use_list) {
        correct_kernel<<<1024, 256, 0, stream>>>(out, list, counter, coef, cap);
    } else {
        correct_full_kernel<<<((HW_ >> 2) + 255)/256, 256, 0, stream>>>(out, mask, coef);
    }
}

// Round 5
// 154.996 us; speedup vs baseline: 1.7957x; 1.1394x over previous
//
#include <hip/hip_runtime.h>

#define HH 2160
#define WW 3840
#define NPATCH 256
#define PSZ 128
#define HW_ (HH*WW)
#define FMSZ (NPATCH*PSZ*PSZ)

#define TW 256
#define TH 8
#define NBX (WW/TW)     // 15
#define NBY (HH/TH)     // 270
#define NB  (NBX*NBY)   // 4050

typedef float fx4 __attribute__((ext_vector_type(4)));

// ws layout: fm | counter | coef | partial[13][NB] | hole list
#define CNT_OFF   ((size_t)FMSZ*4)
#define COEF_OFF  (CNT_OFF + 16)
#define PART_OFF  (COEF_OFF + 48)
#define LIST_OFF  (PART_OFF + ((size_t)13*NB*4 + 63)/64*64)

// ---------------- feather: separable 9-tap gaussian, zero-padded per patch ----------------
// grid (NPATCH, 4): each block computes 32 output rows with +-4 halo in LDS
__global__ __launch_bounds__(256) void feather_kernel(
        const float* __restrict__ mask, const int* __restrict__ pos_y,
        const int* __restrict__ pos_x, float* __restrict__ fm,
        unsigned int* __restrict__ counter) {
    __shared__ float sm[40*PSZ];
    __shared__ float tp[40*PSZ];
    if (blockIdx.x == 0 && blockIdx.y == 0 && threadIdx.x == 0) *counter = 0u;
    const int n = blockIdx.x;
    const int r0 = blockIdx.y * 32;
    const int y0 = pos_y[n], x0 = pos_x[n];
    float g[9]; float s = 0.f;
    #pragma unroll
    for (int k = 0; k < 9; ++k) { float xx = (k-4)*0.75f; g[k] = expf(-0.5f*xx*xx); s += g[k]; }
    const float inv = 1.f/s;
    #pragma unroll
    for (int k = 0; k < 9; ++k) g[k] *= inv;

    for (int idx = threadIdx.x; idx < 40*PSZ; idx += 256) {
        int l = idx >> 7, j = idx & 127;
        int r = r0 + l - 4;
        sm[idx] = ((unsigned)r < (unsigned)PSZ) ? mask[(y0+r)*WW + (x0+j)] : 0.f;
    }
    __syncthreads();
    for (int idx = threadIdx.x; idx < 40*PSZ; idx += 256) {
        int l = idx >> 7, j = idx & 127;
        float a = 0.f;
        #pragma unroll
        for (int d = -4; d <= 4; ++d) {
            int jj = j + d;
            if (jj >= 0 && jj < PSZ) a += sm[(l<<7)+jj]*g[d+4];
        }
        tp[idx] = a;
    }
    __syncthreads();
    float* o = fm + n*(PSZ*PSZ) + r0*PSZ;
    for (int idx = threadIdx.x; idx < 32*PSZ; idx += 256) {
        int i = idx >> 7, j = idx & 127;
        float a = 0.f;
        #pragma unroll
        for (int d = 0; d < 9; ++d) a += tp[((i+d)<<7)+j]*g[d];
        o[idx] = a;
    }
}

// ---------------- compose: per-pixel ordered fold, partials, hole list ----------------
__global__ __launch_bounds__(256) void compose_kernel(
        const float* __restrict__ orig, const float* __restrict__ patches,
        const float* __restrict__ mask, const int* __restrict__ pos_y,
        const int* __restrict__ pos_x, const float* __restrict__ fm,
        float* __restrict__ out, float* __restrict__ partial,
        unsigned int* __restrict__ counter, unsigned int* __restrict__ list,
        unsigned int cap) {
    __shared__ int ln[NPATCH];
    __shared__ int ly[NPATCH];
    __shared__ int lx[NPATCH];
    __shared__ unsigned long long wm[4];
    __shared__ float red[4][13];
    __shared__ unsigned int hcnt[9];

    const int tid = threadIdx.x;
    const int lane = tid & 63;
    const int wid  = tid >> 6;
    const int tx0 = blockIdx.x * TW;
    const int ty0 = blockIdx.y * TH;

    // ordered (ascending n) list of patches overlapping this 256x8 tile
    {
        const int yn = pos_y[tid], xn = pos_x[tid];
        const bool cov = (yn < ty0 + TH) && (yn + PSZ > ty0) &&
                         (xn < tx0 + TW) && (xn + PSZ > tx0);
        unsigned long long b = __ballot(cov);
        if (lane == 0) wm[wid] = b;
        __syncthreads();
        if (cov) {
            int pos = __popcll(b & ((1ull << lane) - 1ull));
            for (int w = 0; w < wid; ++w) pos += __popcll(wm[w]);
            ln[pos] = tid; ly[pos] = yn; lx[pos] = xn;
        }
        __syncthreads();
    }
    const int cnt = __popcll(wm[0]) + __popcll(wm[1]) + __popcll(wm[2]) + __popcll(wm[3]);

    const int x0 = tx0 + lane * 4;          // each thread owns a pixel quad, 2 rows

    float a_cnt = 0.f;
    float so1x=0,so1y=0,so1z=0, so2x=0,so2y=0,so2z=0;
    float sf1x=0,sf1y=0,sf1z=0, sf2x=0,sf2y=0,sf2z=0;
    unsigned int hb[2];
    int qq[2];

    const fx4* __restrict__ mask4 = (const fx4*)mask;
    const fx4* __restrict__ orig4 = (const fx4*)orig;
    fx4* __restrict__ out4 = (fx4*)out;

    #pragma unroll
    for (int rr = 0; rr < 2; ++rr) {
        const int y = ty0 + wid * 2 + rr;
        const int q = (y*WW + x0) >> 2;
        qq[rr] = q;
        const fx4 m = mask4[q];
        fx4 v0 = __builtin_nontemporal_load(&orig4[q]);
        fx4 v1 = __builtin_nontemporal_load(&orig4[(HW_ >> 2) + q]);
        fx4 v2 = __builtin_nontemporal_load(&orig4[((2*HW_) >> 2) + q]);

        const float nhx = 1.f-m.x, nhy = 1.f-m.y, nhz = 1.f-m.z, nhw = 1.f-m.w;
        hb[rr] = (unsigned)(m.x!=0.f) | ((unsigned)(m.y!=0.f)<<1)
               | ((unsigned)(m.z!=0.f)<<2) | ((unsigned)(m.w!=0.f)<<3);
        a_cnt += nhx+nhy+nhz+nhw;
        so1x += v0.x*nhx+v0.y*nhy+v0.z*nhz+v0.w*nhw;
        so2x += v0.x*v0.x*nhx+v0.y*v0.y*nhy+v0.z*v0.z*nhz+v0.w*v0.w*nhw;
        so1y += v1.x*nhx+v1.y*nhy+v1.z*nhz+v1.w*nhw;
        so2y += v1.x*v1.x*nhx+v1.y*v1.y*nhy+v1.z*v1.z*nhz+v1.w*v1.w*nhw;
        so1z += v2.x*nhx+v2.y*nhy+v2.z*nhz+v2.w*nhw;
        so2z += v2.x*v2.x*nhx+v2.y*v2.y*nhy+v2.z*v2.z*nhz+v2.w*v2.w*nhw;

        for (int k = 0; k < cnt; ++k) {
            const int dy = y - ly[k];
            if ((unsigned)dy >= (unsigned)PSZ) continue;
            const int dx0 = x0 - lx[k];
            if (dx0 <= -4 || dx0 >= PSZ) continue;
            const int nn = ln[k];
            const int rowb = dy << 7;
            const float* __restrict__ fmp = fm + nn*(PSZ*PSZ) + rowb;
            const float* __restrict__ pp  = patches + nn*(3*PSZ*PSZ) + rowb;
            #define BLEND(J, MX) { \
                const int dx = dx0 + J; \
                if ((unsigned)dx < (unsigned)PSZ) { \
                    const float f = fmp[dx]; const float of = 1.f - f; \
                    v0.MX = v0.MX*of + pp[dx]*f; \
                    v1.MX = v1.MX*of + pp[dx + PSZ*PSZ]*f; \
                    v2.MX = v2.MX*of + pp[dx + 2*PSZ*PSZ]*f; \
                } }
            BLEND(0, x) BLEND(1, y) BLEND(2, z) BLEND(3, w)
            #undef BLEND
        }

        __builtin_nontemporal_store(v0, &out4[q]);
        __builtin_nontemporal_store(v1, &out4[(HW_ >> 2) + q]);
        __builtin_nontemporal_store(v2, &out4[((2*HW_) >> 2) + q]);

        sf1x += v0.x*nhx+v0.y*nhy+v0.z*nhz+v0.w*nhw;
        sf2x += v0.x*v0.x*nhx+v0.y*v0.y*nhy+v0.z*v0.z*nhz+v0.w*v0.w*nhw;
        sf1y += v1.x*nhx+v1.y*nhy+v1.z*nhz+v1.w*nhw;
        sf2y += v1.x*v1.x*nhx+v1.y*v1.y*nhy+v1.z*v1.z*nhz+v1.w*v1.w*nhw;
        sf1z += v2.x*nhx+v2.y*nhy+v2.z*nhz+v2.w*nhw;
        sf2z += v2.x*v2.x*nhx+v2.y*v2.y*nhy+v2.z*v2.z*nhz+v2.w*v2.w*nhw;
    }

    // --- tail: hole ballots + stats shuffles share one barrier window ---
    const unsigned long long bal0 = __ballot(hb[0] != 0u);
    const unsigned long long bal1 = __ballot(hb[1] != 0u);
    if (lane == 0) { hcnt[wid*2] = (unsigned)__popcll(bal0); hcnt[wid*2+1] = (unsigned)__popcll(bal1); }
    __syncthreads();
    if (tid == 0) {                          // overlapped with other waves' shuffles
        unsigned s = 0;
        #pragma unroll
        for (int i = 0; i < 8; ++i) { unsigned c = hcnt[i]; hcnt[i] = s; s += c; }
        hcnt[8] = atomicAdd(counter, s);
    }
    float vals[13] = {a_cnt, so1x,so1y,so1z, so2x,so2y,so2z,
                      sf1x,sf1y,sf1z, sf2x,sf2y,sf2z};
    #pragma unroll
    for (int v = 0; v < 13; ++v) {
        float t = vals[v];
        t += __shfl_down(t, 32); t += __shfl_down(t, 16);
        t += __shfl_down(t, 8);  t += __shfl_down(t, 4);
        t += __shfl_down(t, 2);  t += __shfl_down(t, 1);
        if (lane == 0) red[wid][v] = t;
    }
    __syncthreads();
    {
        const unsigned base = hcnt[8];
        const unsigned long long lmask = (1ull << lane) - 1ull;
        if (hb[0]) {
            unsigned p = base + hcnt[wid*2] + (unsigned)__popcll(bal0 & lmask);
            if (p < cap) list[p] = ((unsigned)qq[0] << 4) | hb[0];
        }
        if (hb[1]) {
            unsigned p = base + hcnt[wid*2+1] + (unsigned)__popcll(bal1 & lmask);
            if (p < cap) list[p] = ((unsigned)qq[1] << 4) | hb[1];
        }
    }
    if (tid < 13) {
        const int bid = blockIdx.y * NBX + blockIdx.x;
        partial[tid*NB + bid] = red[0][tid] + red[1][tid] + red[2][tid] + red[3][tid];
    }
}

// ---------------- finalize: 13 waves, one per statistic; thread 0 emits coefs ----------------
__global__ __launch_bounds__(832) void finalize_kernel(
        const float* __restrict__ partial, float* __restrict__ coef) {
    __shared__ double tot[13];
    const int w = threadIdx.x >> 6;          // 0..12
    const int lane = threadIdx.x & 63;
    const float* p = partial + w*NB;
    double s0 = 0.0, s1 = 0.0;
    int b = lane;
    for (; b + 64 < NB; b += 128) { s0 += (double)p[b]; s1 += (double)p[b+64]; }
    if (b < NB) s0 += (double)p[b];
    double t = s0 + s1;
    t += __shfl_down(t, 32); t += __shfl_down(t, 16);
    t += __shfl_down(t, 8);  t += __shfl_down(t, 4);
    t += __shfl_down(t, 2);  t += __shfl_down(t, 1);
    if (lane == 0) tot[w] = t;
    __syncthreads();
    if (threadIdx.x == 0) {
        const double cnt = tot[0];
        for (int c = 0; c < 3; ++c) {
            double om = tot[1+c]/cnt;
            double ov = tot[4+c]/cnt - om*om;
            double os = sqrt(ov > 0.0 ? ov : 0.0);
            double fmn = tot[7+c]/cnt;
            double fv = tot[10+c]/cnt - fmn*fmn;
            double fs = sqrt(fv > 0.0 ? fv : 0.0);
            coef[c]   = (float)(os/(fs + 1e-8));
            coef[3+c] = (float)fmn;
            coef[6+c] = (float)om;
        }
    }
}

// ---------------- correct: only listed hole quads, no mask read ----------------
__global__ __launch_bounds__(256) void correct_kernel(
        float* __restrict__ out, const unsigned int* __restrict__ list,
        const unsigned int* __restrict__ counter, const float* __restrict__ coef,
        unsigned int cap) {
    unsigned n = *counter; if (n > cap) n = cap;
    const float r0 = coef[0], r1 = coef[1], r2 = coef[2];
    const float f0 = coef[3], f1 = coef[4], f2 = coef[5];
    const float o0 = coef[6], o1 = coef[7], o2 = coef[8];
    fx4* __restrict__ out4 = (fx4*)out;
    for (unsigned i = blockIdx.x*256u + threadIdx.x; i < n; i += gridDim.x*256u) {
        const unsigned e = list[i];
        const unsigned q = e >> 4, bits = e & 15u;
        fx4 v0 = out4[q];
        fx4 v1 = out4[(HW_>>2)+q];
        fx4 v2 = out4[((2*HW_)>>2)+q];
        if (bits & 1u) { v0.x=(v0.x-f0)*r0+o0; v1.x=(v1.x-f1)*r1+o1; v2.x=(v2.x-f2)*r2+o2; }
        if (bits & 2u) { v0.y=(v0.y-f0)*r0+o0; v1.y=(v1.y-f1)*r1+o1; v2.y=(v2.y-f2)*r2+o2; }
        if (bits & 4u) { v0.z=(v0.z-f0)*r0+o0; v1.z=(v1.z-f1)*r1+o1; v2.z=(v2.z-f2)*r2+o2; }
        if (bits & 8u) { v0.w=(v0.w-f0)*r0+o0; v1.w=(v1.w-f1)*r1+o1; v2.w=(v2.w-f2)*r2+o2; }
        out4[q] = v0;
        out4[(HW_>>2)+q] = v1;
        out4[((2*HW_)>>2)+q] = v2;
    }
}

// ---------------- fallback correct (mask-based) if ws too small for list ----------------
__global__ __launch_bounds__(256) void correct_full_kernel(
        float* __restrict__ out, const float* __restrict__ mask,
        const float* __restrict__ coef) {
    const int q = blockIdx.x * 256 + threadIdx.x;
    if (q >= (HW_ >> 2)) return;
    const fx4 m = ((const fx4*)mask)[q];
    if (m.x == 0.f && m.y == 0.f && m.z == 0.f && m.w == 0.f) return;
    fx4* __restrict__ out4 = (fx4*)out;
    #pragma unroll
    for (int c = 0; c < 3; ++c) {
        const float ratio = coef[c], fmn = coef[3+c], om = coef[6+c];
        fx4 v = out4[c*(HW_ >> 2) + q];
        if (m.x != 0.f) v.x = (v.x - fmn)*ratio + om;
        if (m.y != 0.f) v.y = (v.y - fmn)*ratio + om;
        if (m.z != 0.f) v.z = (v.z - fmn)*ratio + om;
        if (m.w != 0.f) v.w = (v.w - fmn)*ratio + om;
        out4[c*(HW_ >> 2) + q] = v;
    }
}

extern "C" void kernel_launch(void* const* d_in, const int* in_sizes, int n_in,
                              void* d_out, int out_size, void* d_ws, size_t ws_size,
                              hipStream_t stream) {
    const float* orig    = (const float*)d_in[0];
    const float* patches = (const float*)d_in[1];
    const float* mask    = (const float*)d_in[2];
    const int*   pos_y   = (const int*)d_in[3];
    const int*   pos_x   = (const int*)d_in[4];
    float* out = (float*)d_out;

    float*        fm      = (float*)d_ws;
    unsigned int* counter = (unsigned int*)((char*)d_ws + CNT_OFF);
    float*        coef    = (float*)((char*)d_ws + COEF_OFF);
    float*        partial = (float*)((char*)d_ws + PART_OFF);
    unsigned int* list    = (unsigned int*)((char*)d_ws + LIST_OFF);

    unsigned int cap = 0;
    if (ws_size > LIST_OFF) {
        size_t avail = (ws_size - LIST_OFF) / 4;
        cap = (avail > 2097152u) ? 2097152u : (unsigned int)avail;
    }
    const bool use_list = (cap >= 480000u);   // ~384K expected hole quads
    if (!use_list) cap = 0;

    dim3 fg(NPATCH, 4);
    feather_kernel<<<fg, 256, 0, stream>>>(mask, pos_y, pos_x, fm, counter);
    dim3 g(NBX, NBY);
    compose_kernel<<<g, 256, 0, stream>>>(orig, patches, mask, pos_y, pos_x, fm,
                                          out, partial, counter, list, cap);
    finalize_kernel<<<1, 832, 0, stream>>>(partial, coef);
    if (use_list) {
        correct_kernel<<<768, 256, 0, stream>>>(out, list, counter, coef, cap);
    } else {
        correct_full_kernel<<<((HW_ >> 2) + 255)/256, 256, 0, stream>>>(out, mask, coef);
    }
}